// Round 1
// 195.715 us; speedup vs baseline: 1.0420x; 1.0420x over previous
//
#include <hip/hip_runtime.h>

// IBRNet aggregator R9: R8 with LDS cut 13312 -> 10240 B (16 blocks/CU, was 12).
//  - KP 104 -> 80: rows hold 64 working f16 ch + 8 gf slots [64:72) + 4-float
//    gap [72:80).
//  - base1 split: W1[:,0:64]@gf done as an 8-MFMA per-voxel GEMM (B col =
//    nlo&7, result kept in regs as accgf and added as per-col bias);
//    staged base1 GEMM is now K=32 (feats only). mean/var stored compactly
//    (8 vox x 64 k) in the [64:72) slots instead of broadcast to 8 cols.
//  - layout: feats->[0:32); h->[0:64); x->[32:64); vis-chain in-place [0:32);
//    fp32 stats alias rows {4v..4v+3} x [0:32) (dead after P8).
//  - __launch_bounds__(64,4): 4 waves/EU = 16 blocks/CU, VGPR capped at 128.
// Everything else identical to R8 (single wave, barrier-free, n-major cols,
// XCD swizzle, f16 weights preconverted into d_ws).

#define G3 32768
#define KP 80

typedef _Float16 h8 __attribute__((ext_vector_type(8)));
typedef _Float16 h4 __attribute__((ext_vector_type(4)));
typedef _Float16 h2 __attribute__((ext_vector_type(2)));
typedef float f4 __attribute__((ext_vector_type(4)));
typedef float f2 __attribute__((ext_vector_type(2)));
typedef float f4a __attribute__((ext_vector_type(4), aligned(4)));

#define WB() __builtin_amdgcn_wave_barrier()

__device__ __forceinline__ float eluf(float x) {
    return x > 0.0f ? x : __expf(x) - 1.0f;
}
__device__ __forceinline__ float sigmoidf(float x) {
    return 1.0f / (1.0f + __expf(-x));
}
__device__ __forceinline__ float red8v(float v) {
    v += __shfl_xor(v, 8, 64);
    v += __shfl_xor(v, 16, 64);
    v += __shfl_xor(v, 32, 64);
    return v;
}

// d_ws layout (f16 element offsets)
#define WS_BW1G 0      // base_w1 gf part   [64][64] (cols 0..63)
#define WS_BW1F 4096   // base_w1 feat part [64][32] (cols 64..95)
#define WS_BW2 6144    // base_w2 [32][64]
#define WS_VW1 8192    // vis_w1  [32][32]
#define WS_VW2 9216    // vis_w2  [48][32], rows 33..47 zeroed
#define WS_V2W1 10752  // vis2_w1 [32][32]

__global__ void prep_kernel(const float* __restrict__ bw1,
                            const float* __restrict__ bw2,
                            const float* __restrict__ vw1,
                            const float* __restrict__ vw2,
                            const float* __restrict__ v2w1,
                            _Float16* __restrict__ wh) {
    int t = blockIdx.x * blockDim.x + threadIdx.x;
    int stride = gridDim.x * blockDim.x;
    for (int i = t; i < 4096; i += stride) {
        int o = i >> 6, k = i & 63;
        wh[WS_BW1G + i] = (_Float16)bw1[o * 96 + k];
    }
    for (int i = t; i < 2048; i += stride) {
        int o = i >> 5, k = i & 31;
        wh[WS_BW1F + i] = (_Float16)bw1[o * 96 + 64 + k];
    }
    for (int i = t; i < 2048; i += stride) wh[WS_BW2 + i] = (_Float16)bw2[i];
    for (int i = t; i < 1024; i += stride) wh[WS_VW1 + i] = (_Float16)vw1[i];
    for (int i = t; i < 1536; i += stride)
        wh[WS_VW2 + i] = (i < 1056) ? (_Float16)vw2[i] : (_Float16)0.0f;
    for (int i = t; i < 1024; i += stride) wh[WS_V2W1 + i] = (_Float16)v2w1[i];
}

// One 2-tile pass of a layer: tiles {pass*2, pass*2+1}, MT M-tiles of 16.
template <int K, int KS, int MT>
__device__ __forceinline__ void mfma_pass(const _Float16* __restrict__ Wf,
                                          const _Float16* __restrict__ Y,
                                          int srck0, int pass, int lane,
                                          f4 acc[2][4]) {
    const int q = lane >> 4, nlo = lane & 15;
    h8 bf[2][KS];
#pragma unroll
    for (int j = 0; j < 2; ++j) {
        const _Float16* yc =
            Y + ((pass * 2 + j) * 16 + nlo) * KP + srck0 + q * 8;
#pragma unroll
        for (int kt = 0; kt < KS; ++kt) bf[j][kt] = *(const h8*)(yc + kt * 32);
    }
#pragma unroll
    for (int mt = 0; mt < MT; ++mt) {
        h8 af[KS];
#pragma unroll
        for (int kt = 0; kt < KS; ++kt)
            af[kt] = *(const h8*)(Wf + (mt * 16 + nlo) * K + q * 8 + kt * 32);
#pragma unroll
        for (int j = 0; j < 2; ++j)
#pragma unroll
            for (int kt = 0; kt < KS; ++kt)
                acc[j][mt] = __builtin_amdgcn_mfma_f32_16x16x32_f16(
                    af[kt], bf[j][kt], acc[j][mt], 0, 0, 0);
    }
}

template <int MT>
__device__ __forceinline__ void epi_pass(f4 acc[2][4],
                                         const float* __restrict__ bias,
                                         _Float16* __restrict__ Y, int dstk0,
                                         int pass, int lane) {
    const int q = lane >> 4, nlo = lane & 15;
#pragma unroll
    for (int j = 0; j < 2; ++j) {
        const int col = (pass * 2 + j) * 16 + nlo;
#pragma unroll
        for (int mt = 0; mt < MT; ++mt) {
            f4 bb = *(const f4*)(bias + mt * 16 + q * 4);
            h4 hv;
#pragma unroll
            for (int r = 0; r < 4; ++r)
                hv[r] = (_Float16)eluf(acc[j][mt][r] + bb[r]);
            *(h4*)(Y + col * KP + dstk0 + mt * 16 + q * 4) = hv;
        }
    }
}

__global__ __launch_bounds__(64, 4) void ibr_mfma(
    const float* __restrict__ features, const float* __restrict__ mask,
    const float* __restrict__ vdepth, const float* __restrict__ vdir,
    const float* __restrict__ rde_w1, const float* __restrict__ rde_b1,
    const float* __restrict__ rde_w2, const float* __restrict__ rde_b2,
    const float* __restrict__ base_b1, const float* __restrict__ base_b2,
    const float* __restrict__ vis_b1, const float* __restrict__ vis_b2,
    const float* __restrict__ vis2_b1, const float* __restrict__ vis2_w2,
    const float* __restrict__ vis2_b2, const float* __restrict__ stat_w,
    const float* __restrict__ stat_b, const _Float16* __restrict__ wh,
    float* __restrict__ out) {
    __shared__ _Float16 Y[64 * KP];  // 10240 B -- the ONLY LDS

// per-col scalar gap: {mval, wtc, visn, wt2c} at Y row tail [72:80)
#define GAPF(col) ((float*)(Y + (col)*KP + 72))

    const int lane = threadIdx.x;
    const int n = lane >> 3, vi = lane & 7;  // col == lane == n*8+vi
    const int blk = blockIdx.x;
    const int b = blk >> 12;
    const int i = blk & 4095;
    // XCD swizzle: same-XCD blocks (i&7) cover contiguous voxel spans.
    const int v0 = (((i & 7) << 9) | (i >> 3)) << 3;
    const int bn = b * 8 + n;
    const int v = v0 + vi;

    // ---- P0: loads, per-lane rde MLP, wt, f -> Y[0:32) ---------------------
    const float m = mask[bn * G3 + v];
    const float r0 = vdir[(bn * 3 + 0) * G3 + v];
    const float r1 = vdir[(bn * 3 + 1) * G3 + v];
    const float r2 = vdir[(bn * 3 + 2) * G3 + v];
    const float r3 = vdepth[bn * G3 + v];
    float f[32];
#pragma unroll
    for (int c = 0; c < 32; ++c) f[c] = features[(bn * 32 + c) * G3 + v];

    float h16[16];
#pragma unroll
    for (int o = 0; o < 16; ++o) {
        float a = rde_b1[o] + rde_w1[o * 4 + 0] * r0 + rde_w1[o * 4 + 1] * r1 +
                  rde_w1[o * 4 + 2] * r2 + rde_w1[o * 4 + 3] * r3;
        h16[o] = eluf(a);
    }
#pragma unroll
    for (int o = 0; o < 32; ++o) {
        float a = rde_b2[o];
#pragma unroll
        for (int c = 0; c < 16; ++c) a += rde_w2[o * 16 + c] * h16[c];
        f[o] += eluf(a);
    }

    const float msum = red8v(m);
    const float invA = 1.0f / (msum + 1e-8f);
    const float wt = m * invA;
    const float sA = msum * invA;  // own-voxel sum of weights
    {
        f2 mw = {m, wt};
        *(f2*)GAPF(lane) = mw;  // gap[0]=mval, gap[1]=wtc
    }

    {
        _Float16* yl = Y + lane * KP;
#pragma unroll
        for (int g = 0; g < 4; ++g) {
            h8 t;
#pragma unroll
            for (int e = 0; e < 8; ++e) t[e] = (_Float16)f[g * 8 + e];
            *(h8*)(yl + g * 8) = t;
        }
    }
    WB();

    // ---- P1: compact gf: mean (k 0..31) + var (k 32..63) per voxel ---------
    // gf[vox][k] lives at Y[vox*8 + (k>>3)][64 + (k&7)]
    {
        const int pv = lane >> 3, u = lane & 7;
        const float kA = 2.0f - __shfl(sA, pv, 64);  // lane pv owns vi=pv
#pragma unroll
        for (int t2 = 0; t2 < 2; ++t2) {
            const int dw = u + 8 * t2;  // channel-pair index 0..15
            float s0 = 0.f, s1 = 0.f, q0 = 0.f, q1 = 0.f;
#pragma unroll
            for (int nn = 0; nn < 8; ++nn) {
                const int col = nn * 8 + pv;
                h2 xv = *(const h2*)(Y + col * KP + dw * 2);
                const float wv = GAPF(col)[1];
                const float x0 = (float)xv[0], x1 = (float)xv[1];
                s0 += wv * x0; q0 += wv * x0 * x0;
                s1 += wv * x1; q1 += wv * x1 * x1;
            }
            h2 hm = {(_Float16)s0, (_Float16)s1};
            h2 hv = {(_Float16)(q0 - s0 * s0 * kA),
                     (_Float16)(q1 - s1 * s1 * kA)};
            // mean k=2dw -> row pv*8+(dw>>2); var k=32+2dw -> +4 rows
            _Float16* g =
                Y + (pv * 8 + (dw >> 2)) * KP + 64 + ((2 * dw) & 7);
            *(h2*)g = hm;
            *(h2*)(g + 4 * KP) = hv;
        }
    }
    WB();

    // ---- P2: gf GEMM (8 MFMA, per-voxel bias in regs) + base1 feats 32->64 -
    {
        const int q = lane >> 4, nlo = lane & 15, vox = nlo & 7;
        f4 accgf[4] = {};
        {
            // B frag k = q*8 + kt*32 -> gf row vox*8 + kt*4 + q
            h8 bg0 = *(const h8*)(Y + (vox * 8 + q) * KP + 64);
            h8 bg1 = *(const h8*)(Y + (vox * 8 + 4 + q) * KP + 64);
#pragma unroll
            for (int mt = 0; mt < 4; ++mt) {
                h8 a0 =
                    *(const h8*)(wh + WS_BW1G + (mt * 16 + nlo) * 64 + q * 8);
                h8 a1 = *(const h8*)(wh + WS_BW1G + (mt * 16 + nlo) * 64 +
                                     q * 8 + 32);
                accgf[mt] = __builtin_amdgcn_mfma_f32_16x16x32_f16(
                    a0, bg0, accgf[mt], 0, 0, 0);
                accgf[mt] = __builtin_amdgcn_mfma_f32_16x16x32_f16(
                    a1, bg1, accgf[mt], 0, 0, 0);
            }
        }
#pragma unroll
        for (int pass = 0; pass < 2; ++pass) {
            f4 acc[2][4] = {};
            mfma_pass<32, 1, 4>(wh + WS_BW1F, Y, 0, pass, lane, acc);
#pragma unroll
            for (int j = 0; j < 2; ++j) {
                const int col = (pass * 2 + j) * 16 + nlo;
#pragma unroll
                for (int mt = 0; mt < 4; ++mt) {
                    f4 bb = *(const f4*)(base_b1 + mt * 16 + q * 4);
                    h4 hv;
#pragma unroll
                    for (int r = 0; r < 4; ++r)
                        hv[r] =
                            (_Float16)eluf(acc[j][mt][r] + accgf[mt][r] + bb[r]);
                    *(h4*)(Y + col * KP + mt * 16 + q * 4) = hv;
                }
            }
        }
    }
    WB();

    // ---- P3: base2 64 -> 32; x -> [32:64), x*wt -> [0:32) ------------------
#pragma unroll
    for (int pass = 0; pass < 2; ++pass) {
        f4 acc[2][4] = {};
        mfma_pass<64, 2, 2>(wh + WS_BW2, Y, 0, pass, lane, acc);
        const int q = lane >> 4, nlo = lane & 15;
#pragma unroll
        for (int j = 0; j < 2; ++j) {
            const int col = (pass * 2 + j) * 16 + nlo;
            const float w = GAPF(col)[1];
#pragma unroll
            for (int mt = 0; mt < 2; ++mt) {
                f4 bb = *(const f4*)(base_b2 + mt * 16 + q * 4);
                h4 hx, hxw;
#pragma unroll
                for (int r = 0; r < 4; ++r) {
                    const float xv = eluf(acc[j][mt][r] + bb[r]);
                    hx[r] = (_Float16)xv;
                    hxw[r] = (_Float16)(xv * w);
                }
                *(h4*)(Y + col * KP + 32 + mt * 16 + q * 4) = hx;
                *(h4*)(Y + col * KP + mt * 16 + q * 4) = hxw;
            }
        }
    }
    WB();

    // ---- P4: vis1 32 -> 32 (in place [0:32)) -------------------------------
#pragma unroll
    for (int pass = 0; pass < 2; ++pass) {
        f4 acc[2][4] = {};
        mfma_pass<32, 1, 2>(wh + WS_VW1, Y, 0, pass, lane, acc);
        epi_pass<2>(acc, vis_b1, Y, 0, pass, lane);
    }
    WB();

    // ---- P5: vis2 32 -> 33; x_res -> [0:32), visn --------------------------
#pragma unroll
    for (int pass = 0; pass < 2; ++pass) {
        f4 acc[2][4] = {};
        mfma_pass<32, 1, 3>(wh + WS_VW2, Y, 0, pass, lane, acc);
        const int q = lane >> 4, nlo = lane & 15;
#pragma unroll
        for (int j = 0; j < 2; ++j) {
            const int col = (pass * 2 + j) * 16 + nlo;
#pragma unroll
            for (int mt = 0; mt < 2; ++mt) {
                f4 bb = *(const f4*)(vis_b2 + mt * 16 + q * 4);
                h4 hv;
#pragma unroll
                for (int r = 0; r < 4; ++r)
                    hv[r] = (_Float16)eluf(acc[j][mt][r] + bb[r]);
                *(h4*)(Y + col * KP + mt * 16 + q * 4) = hv;
            }
            if (q == 0) {  // global row 32: vis channel
                const float vv = acc[j][2][0] + vis_b2[32];
                GAPF(col)[2] = sigmoidf(eluf(vv)) * GAPF(col)[0];
            }
        }
    }
    WB();

    // ---- P6: x += x_res -> [32:64), x*visn -> [0:32) -----------------------
    {
        const int pv = lane >> 3, u = lane & 7;
#pragma unroll
        for (int nn = 0; nn < 8; ++nn) {
            const int col = nn * 8 + pv;
            const float vn = GAPF(col)[2];
#pragma unroll
            for (int t2 = 0; t2 < 2; ++t2) {
                const int dw = u + 8 * t2;
                h2 xr = *(const h2*)(Y + col * KP + dw * 2);
                h2 xo = *(const h2*)(Y + col * KP + 32 + dw * 2);
                const float x0 = (float)xo[0] + (float)xr[0];
                const float x1 = (float)xo[1] + (float)xr[1];
                h2 hx = {(_Float16)x0, (_Float16)x1};
                h2 hxv = {(_Float16)(x0 * vn), (_Float16)(x1 * vn)};
                *(h2*)(Y + col * KP + 32 + dw * 2) = hx;
                *(h2*)(Y + col * KP + dw * 2) = hxv;
            }
        }
    }
    WB();

    // ---- P7: vis2_1 32 -> 32 (in place [0:32)) -----------------------------
#pragma unroll
    for (int pass = 0; pass < 2; ++pass) {
        f4 acc[2][4] = {};
        mfma_pass<32, 1, 2>(wh + WS_V2W1, Y, 0, pass, lane, acc);
        epi_pass<2>(acc, vis2_b1, Y, 0, pass, lane);
    }
    WB();

    // ---- P8: vis2_2 (VALU, own col, reads [0:32)) -> visv, wt2 -------------
    float sCl;  // per-lane: sum of wt2 over views for its voxel
    {
        const _Float16* yc = Y + lane * KP;
        float a0 = vis2_b2[0], a1 = 0.f;
#pragma unroll
        for (int t = 0; t < 16; ++t) {
            h2 p = *(const h2*)(yc + t * 2);
            if (t & 1)
                a1 += vis2_w2[t * 2] * (float)p[0] +
                      vis2_w2[t * 2 + 1] * (float)p[1];
            else
                a0 += vis2_w2[t * 2] * (float)p[0] +
                      vis2_w2[t * 2 + 1] * (float)p[1];
        }
        const float visv = sigmoidf(a0 + a1) * m;
        const float b0 = red8v(visv);
        const float invC = 1.0f / (b0 + 1e-8f);
        GAPF(lane)[3] = visv * invC;  // wt2
        sCl = b0 * invC;
    }
    WB();

    // ---- P9: vis-weighted mean2/var2 (fp32) -> aliased stats rows ----------
    // mean2[vi] e0..31 -> rows {4vi,4vi+1} [0:32); var2[vi] -> rows {4vi+2,4vi+3}
    {
        const int pv = lane >> 3, u = lane & 7;
        const float kC = 2.0f - __shfl(sCl, pv, 64);
#pragma unroll
        for (int t2 = 0; t2 < 2; ++t2) {
            const int dw = u + 8 * t2;
            float s0 = 0.f, s1 = 0.f, q0 = 0.f, q1 = 0.f;
#pragma unroll
            for (int nn = 0; nn < 8; ++nn) {
                const int col = nn * 8 + pv;
                h2 xv = *(const h2*)(Y + col * KP + 32 + dw * 2);
                const float wv = GAPF(col)[3];
                const float x0 = (float)xv[0], x1 = (float)xv[1];
                s0 += wv * x0; q0 += wv * x0 * x0;
                s1 += wv * x1; q1 += wv * x1 * x1;
            }
            f2 mp = {s0, s1};
            f2 vp = {q0 - s0 * s0 * kC, q1 - s1 * s1 * kC};
            *(f2*)((float*)(Y + (4 * pv + t2) * KP) + 2 * u) = mp;
            *(f2*)((float*)(Y + (4 * pv + 2 + t2) * KP) + 2 * u) = vp;
        }
    }
    WB();

    // ---- P10: stat layer (VALU), lane = (o, half), 4 voxels/lane -----------
    {
        const int o = lane >> 1;
        const int vi0 = (lane & 1) * 4;
        const float wm_own = sCl * 0.125f;  // own-voxel mean of weight
        const float* row = stat_w + o * 65;
        float wmv[4];
#pragma unroll
        for (int k2 = 0; k2 < 4; ++k2) wmv[k2] = __shfl(wm_own, vi0 + k2, 64);
        float pr[4];
#pragma unroll
        for (int k2 = 0; k2 < 4; ++k2) pr[k2] = stat_b[o];
#pragma unroll
        for (int c4 = 0; c4 < 8; ++c4) {
            f4a wr = *(const f4a*)(row + c4 * 4);
            f4a ur = *(const f4a*)(row + 32 + c4 * 4);
#pragma unroll
            for (int k2 = 0; k2 < 4; ++k2) {
                const float* sm =
                    (const float*)(Y + (4 * (vi0 + k2) + (c4 >> 2)) * KP) +
                    (c4 & 3) * 4;
                const float* sv =
                    (const float*)(Y + (4 * (vi0 + k2) + 2 + (c4 >> 2)) * KP) +
                    (c4 & 3) * 4;
                f4 a = *(const f4*)sm;
                f4 bvv = *(const f4*)sv;
                pr[k2] += wr[0] * a[0] + wr[1] * a[1] + wr[2] * a[2] +
                          wr[3] * a[3] + ur[0] * bvv[0] + ur[1] * bvv[1] +
                          ur[2] * bvv[2] + ur[3] * bvv[3];
            }
        }
        const float wl = row[64];
        f4 res;
#pragma unroll
        for (int k2 = 0; k2 < 4; ++k2)
            res[k2] = eluf(pr[k2] + wl * wmv[k2]);
        *(f4*)(out + ((b * 32 + o) << 15) + v0 + vi0) = res;
    }
#undef GAPF
}

extern "C" void kernel_launch(void* const* d_in, const int* in_sizes, int n_in,
                              void* d_out, int out_size, void* d_ws,
                              size_t ws_size, hipStream_t stream) {
    const float* features = (const float*)d_in[0];
    const float* mask = (const float*)d_in[1];
    const float* vdepth = (const float*)d_in[2];
    const float* vdir = (const float*)d_in[3];
    const float* rde_w1 = (const float*)d_in[4];
    const float* rde_b1 = (const float*)d_in[5];
    const float* rde_w2 = (const float*)d_in[6];
    const float* rde_b2 = (const float*)d_in[7];
    const float* base_w1 = (const float*)d_in[8];
    const float* base_b1 = (const float*)d_in[9];
    const float* base_w2 = (const float*)d_in[10];
    const float* base_b2 = (const float*)d_in[11];
    const float* vis_w1 = (const float*)d_in[12];
    const float* vis_b1 = (const float*)d_in[13];
    const float* vis_w2 = (const float*)d_in[14];
    const float* vis_b2 = (const float*)d_in[15];
    const float* vis2_w1 = (const float*)d_in[16];
    const float* vis2_b1 = (const float*)d_in[17];
    const float* vis2_w2 = (const float*)d_in[18];
    const float* vis2_b2 = (const float*)d_in[19];
    const float* stat_w = (const float*)d_in[20];
    const float* stat_b = (const float*)d_in[21];

    _Float16* wh = (_Float16*)d_ws;
    prep_kernel<<<24, 256, 0, stream>>>(base_w1, base_w2, vis_w1, vis_w2,
                                        vis2_w1, wh);

    // 524288 cols / 64 per block = 8192 single-wave blocks
    ibr_mfma<<<8192, 64, 0, stream>>>(
        features, mask, vdepth, vdir, rde_w1, rde_b1, rde_w2, rde_b2, base_b1,
        base_b2, vis_b1, vis_b2, vis2_b1, vis2_w2, vis2_b2, stat_w, stat_b, wh,
        (float*)d_out);
}